// Round 1
// baseline (823.339 us; speedup 1.0000x reference)
//
#include <hip/hip_runtime.h>

typedef unsigned short u16;
typedef short bf16x8 __attribute__((ext_vector_type(8)));
typedef float f32x4 __attribute__((ext_vector_type(4)));

#define CH 512
#define HW 4096
#define TOKENS 16384
#define NGRP 32

__device__ __forceinline__ u16 f2bf(float f) {
  unsigned u = __float_as_uint(f);
  u += 0x7fffu + ((u >> 16) & 1u);   // round-nearest-even
  return (u16)(u >> 16);
}
__device__ __forceinline__ float bf2f(u16 h) {
  return __uint_as_float(((unsigned)h) << 16);
}

// ---------------- GroupNorm stats: one block per (b,g) ----------------
__global__ void gn_stats(const float* __restrict__ x, float2* __restrict__ stats) {
  int bg = blockIdx.x;              // 0..127
  int b = bg >> 5, g = bg & 31;
  const float* base = x + (size_t)b * HW * CH + g * 16;
  float s = 0.f, s2 = 0.f;
  for (int p = threadIdx.x; p < HW; p += 256) {
    const float4* row = (const float4*)(base + (size_t)p * CH);
#pragma unroll
    for (int q = 0; q < 4; ++q) {
      float4 v = row[q];
      s += v.x + v.y + v.z + v.w;
      s2 += v.x * v.x + v.y * v.y + v.z * v.z + v.w * v.w;
    }
  }
#pragma unroll
  for (int o = 32; o; o >>= 1) { s += __shfl_down(s, o); s2 += __shfl_down(s2, o); }
  __shared__ float rs[4], rs2[4];
  int wid = threadIdx.x >> 6, lane = threadIdx.x & 63;
  if (lane == 0) { rs[wid] = s; rs2[wid] = s2; }
  __syncthreads();
  if (threadIdx.x == 0) {
    float S = rs[0] + rs[1] + rs[2] + rs[3];
    float S2 = rs2[0] + rs2[1] + rs2[2] + rs2[3];
    float mean = S * (1.f / 65536.f);
    float var = S2 * (1.f / 65536.f) - mean * mean;
    stats[bg] = make_float2(mean, rsqrtf(var + 1e-5f));
  }
}

// ---------------- GroupNorm apply -> xn (bf16) ----------------
__global__ void gn_apply(const float* __restrict__ x, const float* __restrict__ gamma,
                         const float* __restrict__ beta, const float2* __restrict__ stats,
                         u16* __restrict__ xn) {
  size_t i = (size_t)blockIdx.x * blockDim.x + threadIdx.x;  // chunk of 8 elems
  size_t e0 = i * 8;
  int c = (int)(e0 & (CH - 1));
  size_t t = e0 >> 9;
  int b = (int)(t >> 12);
  float2 st = stats[b * NGRP + (c >> 4)];
  float4 v0 = *(const float4*)(x + t * CH + c);
  float4 v1 = *(const float4*)(x + t * CH + c + 4);
  float4 g0 = *(const float4*)(gamma + c);
  float4 g1 = *(const float4*)(gamma + c + 4);
  float4 b0 = *(const float4*)(beta + c);
  float4 b1 = *(const float4*)(beta + c + 4);
  float o[8];
  o[0] = (v0.x - st.x) * st.y * g0.x + b0.x;
  o[1] = (v0.y - st.x) * st.y * g0.y + b0.y;
  o[2] = (v0.z - st.x) * st.y * g0.z + b0.z;
  o[3] = (v0.w - st.x) * st.y * g0.w + b0.w;
  o[4] = (v1.x - st.x) * st.y * g1.x + b1.x;
  o[5] = (v1.y - st.x) * st.y * g1.y + b1.y;
  o[6] = (v1.z - st.x) * st.y * g1.z + b1.z;
  o[7] = (v1.w - st.x) * st.y * g1.w + b1.w;
  union { u16 us[8]; uint4 q; } pk;
#pragma unroll
  for (int k = 0; k < 8; ++k) pk.us[k] = f2bf(o[k]);
  *(uint4*)(xn + e0) = pk.q;
}

// ---------------- transpose 512x512 weights fp32 -> bf16 (T[d][c] = W[c][d]) ----------------
__global__ void transpose_w(const float* __restrict__ W0, const float* __restrict__ W1,
                            const float* __restrict__ W2, const float* __restrict__ W3,
                            u16* __restrict__ T0, u16* __restrict__ T1,
                            u16* __restrict__ T2, u16* __restrict__ T3) {
  const float* W; u16* T;
  switch (blockIdx.z) {
    case 0: W = W0; T = T0; break;
    case 1: W = W1; T = T1; break;
    case 2: W = W2; T = T2; break;
    default: W = W3; T = T3; break;
  }
  __shared__ float tile[32][33];
  int tx = threadIdx.x, ty = threadIdx.y;
  int x0 = blockIdx.x * 32, y0 = blockIdx.y * 32;
#pragma unroll
  for (int r = 0; r < 32; r += 8) tile[ty + r][tx] = W[(size_t)(y0 + ty + r) * CH + x0 + tx];
  __syncthreads();
#pragma unroll
  for (int r = 0; r < 32; r += 8) T[(size_t)(x0 + ty + r) * CH + y0 + tx] = f2bf(tile[tx][ty + r]);
}

// ---------------- generic NT GEMM: C[M,N] = scale * A[M,K] * Bt[N,K]^T (+bias) ----------------
// MODE 0: bf16 out, row-major [M][N]
// MODE 1: bf16 out, transposed per-4096-batch: out[(b*CH+n)*HW + (m&4095)]  (V path)
// MODE 2: f32 out + residual add (proj path)
template <int MODE, int BM, int BN>
__global__ __launch_bounds__(256) void gemm_nt(const u16* __restrict__ A,
                                               const u16* __restrict__ Bt,
                                               const float* __restrict__ bias,
                                               const float* __restrict__ residual,
                                               void* __restrict__ Cout,
                                               int M, int N, int K, float scale) {
  constexpr int BK = 64;
  constexpr int LR = 72;              // LDS row stride (shorts): 144B, conflict-free
  constexpr int FM = BM / 32;         // frags per wave (2x2 wave grid)
  constexpr int FN = BN / 32;
  __shared__ __align__(16) u16 lA[BM * LR];
  __shared__ __align__(16) u16 lB[BN * LR];
  const int tid = threadIdx.x;
  const int lane = tid & 63, wid = tid >> 6;
  const int bm = blockIdx.y * BM, bn = blockIdx.x * BN;
  const int wm = (wid >> 1) * (BM / 2), wn = (wid & 1) * (BN / 2);
  const int r0 = lane & 15, h = lane >> 4;

  f32x4 acc[FM][FN] = {};

  for (int kt = 0; kt < K; kt += BK) {
    __syncthreads();
#pragma unroll
    for (int s = 0; s < BM * 8 / 256; ++s) {
      int cid = tid + s * 256;
      int row = cid >> 3, col = (cid & 7) * 8;
      bf16x8 v = *(const bf16x8*)(A + (size_t)(bm + row) * K + kt + col);
      *(bf16x8*)(&lA[row * LR + col]) = v;
    }
#pragma unroll
    for (int s = 0; s < BN * 8 / 256; ++s) {
      int cid = tid + s * 256;
      int row = cid >> 3, col = (cid & 7) * 8;
      bf16x8 v = *(const bf16x8*)(Bt + (size_t)(bn + row) * K + kt + col);
      *(bf16x8*)(&lB[row * LR + col]) = v;
    }
    __syncthreads();
#pragma unroll
    for (int kk = 0; kk < BK; kk += 32) {
      bf16x8 af[FM], bfr[FN];
#pragma unroll
      for (int i = 0; i < FM; ++i)
        af[i] = *(const bf16x8*)(&lA[(wm + i * 16 + r0) * LR + kk + h * 8]);
#pragma unroll
      for (int j = 0; j < FN; ++j)
        bfr[j] = *(const bf16x8*)(&lB[(wn + j * 16 + r0) * LR + kk + h * 8]);
#pragma unroll
      for (int i = 0; i < FM; ++i)
#pragma unroll
        for (int j = 0; j < FN; ++j)
          acc[i][j] = __builtin_amdgcn_mfma_f32_16x16x32_bf16(af[i], bfr[j], acc[i][j], 0, 0, 0);
    }
  }

  // epilogue: D layout col = lane&15, row = (lane>>4)*4 + r
#pragma unroll
  for (int j = 0; j < FN; ++j) {
    int n = bn + wn + j * 16 + r0;
    float bv = bias ? bias[n] : 0.0f;
#pragma unroll
    for (int i = 0; i < FM; ++i) {
      int m0 = bm + wm + i * 16 + h * 4;
      float v[4];
#pragma unroll
      for (int r = 0; r < 4; ++r) v[r] = acc[i][j][r] * scale + bv;
      if constexpr (MODE == 0) {
        u16* C = (u16*)Cout;
#pragma unroll
        for (int r = 0; r < 4; ++r) C[(size_t)(m0 + r) * N + n] = f2bf(v[r]);
      } else if constexpr (MODE == 1) {
        int bb = m0 >> 12, tl = m0 & (HW - 1);
        u16* C = (u16*)Cout + ((size_t)bb * CH + n) * HW + tl;
        union { u16 us[4]; uint2 q; } pk;
#pragma unroll
        for (int r = 0; r < 4; ++r) pk.us[r] = f2bf(v[r]);
        *(uint2*)C = pk.q;
      } else {
        float* C = (float*)Cout;
#pragma unroll
        for (int r = 0; r < 4; ++r) {
          size_t idx = (size_t)(m0 + r) * N + n;
          C[idx] = v[r] + residual[idx];
        }
      }
    }
  }
}

// ---------------- row softmax in-place on bf16 S [HW rows of HW] ----------------
__global__ void softmax_rows(u16* __restrict__ S) {
  const int t = threadIdx.x;
  u16* row = S + (size_t)blockIdx.x * HW;
  float v[16];
  bf16x8 a0 = *((const bf16x8*)row + t * 2);
  bf16x8 a1 = *((const bf16x8*)row + t * 2 + 1);
#pragma unroll
  for (int k = 0; k < 8; ++k) { v[k] = bf2f((u16)a0[k]); v[8 + k] = bf2f((u16)a1[k]); }
  float mx = v[0];
#pragma unroll
  for (int k = 1; k < 16; ++k) mx = fmaxf(mx, v[k]);
#pragma unroll
  for (int o = 32; o; o >>= 1) mx = fmaxf(mx, __shfl_xor(mx, o));
  __shared__ float redm[4], reds[4];
  int wid = t >> 6, lane = t & 63;
  if (lane == 0) redm[wid] = mx;
  __syncthreads();
  mx = fmaxf(fmaxf(redm[0], redm[1]), fmaxf(redm[2], redm[3]));
  float s = 0.f;
#pragma unroll
  for (int k = 0; k < 16; ++k) { v[k] = __expf(v[k] - mx); s += v[k]; }
#pragma unroll
  for (int o = 32; o; o >>= 1) s += __shfl_xor(s, o);
  if (lane == 0) reds[wid] = s;
  __syncthreads();
  s = reds[0] + reds[1] + reds[2] + reds[3];
  float inv = 1.0f / s;
  bf16x8 o0, o1;
#pragma unroll
  for (int k = 0; k < 8; ++k) {
    o0[k] = (short)f2bf(v[k] * inv);
    o1[k] = (short)f2bf(v[8 + k] * inv);
  }
  *((bf16x8*)row + t * 2) = o0;
  *((bf16x8*)row + t * 2 + 1) = o1;
}

extern "C" void kernel_launch(void* const* d_in, const int* in_sizes, int n_in,
                              void* d_out, int out_size, void* d_ws, size_t ws_size,
                              hipStream_t stream) {
  (void)in_sizes; (void)n_in; (void)out_size; (void)ws_size;
  const float* x     = (const float*)d_in[0];
  const float* gamma = (const float*)d_in[1];
  const float* beta  = (const float*)d_in[2];
  const float* Wq    = (const float*)d_in[3];
  const float* bq    = (const float*)d_in[4];
  const float* Wk    = (const float*)d_in[5];
  const float* bk    = (const float*)d_in[6];
  const float* Wv    = (const float*)d_in[7];
  const float* bv    = (const float*)d_in[8];
  const float* Wp    = (const float*)d_in[9];
  const float* bp    = (const float*)d_in[10];
  float* out = (float*)d_out;

  char* ws = (char*)d_ws;
  size_t off = 0;
  auto alloc = [&](size_t bytes) -> void* {
    void* p = ws + off;
    off += (bytes + 255) & ~(size_t)255;
    return p;
  };
  float2* stats = (float2*)alloc(128 * sizeof(float2));
  u16* xn  = (u16*)alloc((size_t)TOKENS * CH * 2);
  u16* Qb  = (u16*)alloc((size_t)TOKENS * CH * 2);
  u16* Kb  = (u16*)alloc((size_t)TOKENS * CH * 2);
  u16* Vt  = (u16*)alloc((size_t)TOKENS * CH * 2);   // [B][CH][HW]
  u16* Ob  = (u16*)alloc((size_t)TOKENS * CH * 2);
  u16* WqT = (u16*)alloc((size_t)CH * CH * 2);
  u16* WkT = (u16*)alloc((size_t)CH * CH * 2);
  u16* WvT = (u16*)alloc((size_t)CH * CH * 2);
  u16* WpT = (u16*)alloc((size_t)CH * CH * 2);
  u16* Sb  = (u16*)alloc((size_t)HW * HW * 2);       // one batch of scores

  gn_stats<<<128, 256, 0, stream>>>(x, stats);
  gn_apply<<<TOKENS * CH / 8 / 256, 256, 0, stream>>>(x, gamma, beta, stats, xn);
  transpose_w<<<dim3(16, 16, 4), dim3(32, 8), 0, stream>>>(Wq, Wk, Wv, Wp, WqT, WkT, WvT, WpT);

  gemm_nt<0, 128, 128><<<dim3(CH / 128, TOKENS / 128), 256, 0, stream>>>(
      xn, WqT, bq, nullptr, Qb, TOKENS, CH, CH, 1.0f);
  gemm_nt<0, 128, 128><<<dim3(CH / 128, TOKENS / 128), 256, 0, stream>>>(
      xn, WkT, bk, nullptr, Kb, TOKENS, CH, CH, 1.0f);
  gemm_nt<1, 128, 128><<<dim3(CH / 128, TOKENS / 128), 256, 0, stream>>>(
      xn, WvT, bv, nullptr, Vt, TOKENS, CH, CH, 1.0f);

  const float scl = 0.044194173824159216f;  // 1/sqrt(512)
  for (int b = 0; b < 4; ++b) {
    gemm_nt<0, 128, 128><<<dim3(HW / 128, HW / 128), 256, 0, stream>>>(
        Qb + (size_t)b * HW * CH, Kb + (size_t)b * HW * CH, nullptr, nullptr, Sb,
        HW, HW, CH, scl);
    softmax_rows<<<HW, 256, 0, stream>>>(Sb);
    gemm_nt<0, 64, 128><<<dim3(CH / 128, HW / 64), 256, 0, stream>>>(
        Sb, Vt + (size_t)b * CH * HW, nullptr, nullptr, Ob + (size_t)b * HW * CH,
        HW, CH, HW, 1.0f);
  }

  gemm_nt<2, 128, 128><<<dim3(CH / 128, TOKENS / 128), 256, 0, stream>>>(
      Ob, WpT, bp, x, out, TOKENS, CH, CH, 1.0f);
}

// Round 2
// 405.080 us; speedup vs baseline: 2.0325x; 2.0325x over previous
//
#include <hip/hip_runtime.h>

typedef unsigned short u16;
typedef short bf16x8 __attribute__((ext_vector_type(8)));
typedef float f32x4 __attribute__((ext_vector_type(4)));

#define CH 512
#define HW 4096
#define TOKENS 16384
#define NGRP 32

__device__ __forceinline__ u16 f2bf(float f) {
  unsigned u = __float_as_uint(f);
  u += 0x7fffu + ((u >> 16) & 1u);   // round-nearest-even
  return (u16)(u >> 16);
}
__device__ __forceinline__ float bf2f(u16 h) {
  return __uint_as_float(((unsigned)h) << 16);
}

// ---------------- GroupNorm stats: one block per (b,g) ----------------
__global__ void gn_stats(const float* __restrict__ x, float2* __restrict__ stats) {
  int bg = blockIdx.x;              // 0..127
  int b = bg >> 5, g = bg & 31;
  const float* base = x + (size_t)b * HW * CH + g * 16;
  float s = 0.f, s2 = 0.f;
  for (int p = threadIdx.x; p < HW; p += 256) {
    const float4* row = (const float4*)(base + (size_t)p * CH);
#pragma unroll
    for (int q = 0; q < 4; ++q) {
      float4 v = row[q];
      s += v.x + v.y + v.z + v.w;
      s2 += v.x * v.x + v.y * v.y + v.z * v.z + v.w * v.w;
    }
  }
#pragma unroll
  for (int o = 32; o; o >>= 1) { s += __shfl_down(s, o); s2 += __shfl_down(s2, o); }
  __shared__ float rs[4], rs2[4];
  int wid = threadIdx.x >> 6, lane = threadIdx.x & 63;
  if (lane == 0) { rs[wid] = s; rs2[wid] = s2; }
  __syncthreads();
  if (threadIdx.x == 0) {
    float S = rs[0] + rs[1] + rs[2] + rs[3];
    float S2 = rs2[0] + rs2[1] + rs2[2] + rs2[3];
    float mean = S * (1.f / 65536.f);
    float var = S2 * (1.f / 65536.f) - mean * mean;
    stats[bg] = make_float2(mean, rsqrtf(var + 1e-5f));
  }
}

// ---------------- GroupNorm apply -> xn (bf16) ----------------
__global__ void gn_apply(const float* __restrict__ x, const float* __restrict__ gamma,
                         const float* __restrict__ beta, const float2* __restrict__ stats,
                         u16* __restrict__ xn) {
  size_t i = (size_t)blockIdx.x * blockDim.x + threadIdx.x;  // chunk of 8 elems
  size_t e0 = i * 8;
  int c = (int)(e0 & (CH - 1));
  size_t t = e0 >> 9;
  int b = (int)(t >> 12);
  float2 st = stats[b * NGRP + (c >> 4)];
  float4 v0 = *(const float4*)(x + t * CH + c);
  float4 v1 = *(const float4*)(x + t * CH + c + 4);
  float4 g0 = *(const float4*)(gamma + c);
  float4 g1 = *(const float4*)(gamma + c + 4);
  float4 b0 = *(const float4*)(beta + c);
  float4 b1 = *(const float4*)(beta + c + 4);
  float o[8];
  o[0] = (v0.x - st.x) * st.y * g0.x + b0.x;
  o[1] = (v0.y - st.x) * st.y * g0.y + b0.y;
  o[2] = (v0.z - st.x) * st.y * g0.z + b0.z;
  o[3] = (v0.w - st.x) * st.y * g0.w + b0.w;
  o[4] = (v1.x - st.x) * st.y * g1.x + b1.x;
  o[5] = (v1.y - st.x) * st.y * g1.y + b1.y;
  o[6] = (v1.z - st.x) * st.y * g1.z + b1.z;
  o[7] = (v1.w - st.x) * st.y * g1.w + b1.w;
  union { u16 us[8]; uint4 q; } pk;
#pragma unroll
  for (int k = 0; k < 8; ++k) pk.us[k] = f2bf(o[k]);
  *(uint4*)(xn + e0) = pk.q;
}

// ---------------- transpose 512x512 weights fp32 -> bf16 (T[d][c] = W[c][d]) ----------------
__global__ void transpose_w(const float* __restrict__ W0, const float* __restrict__ W1,
                            const float* __restrict__ W2, const float* __restrict__ W3,
                            u16* __restrict__ T0, u16* __restrict__ T1,
                            u16* __restrict__ T2, u16* __restrict__ T3) {
  const float* W; u16* T;
  switch (blockIdx.z) {
    case 0: W = W0; T = T0; break;
    case 1: W = W1; T = T1; break;
    case 2: W = W2; T = T2; break;
    default: W = W3; T = T3; break;
  }
  __shared__ float tile[32][33];
  int tx = threadIdx.x, ty = threadIdx.y;
  int x0 = blockIdx.x * 32, y0 = blockIdx.y * 32;
#pragma unroll
  for (int r = 0; r < 32; r += 8) tile[ty + r][tx] = W[(size_t)(y0 + ty + r) * CH + x0 + tx];
  __syncthreads();
#pragma unroll
  for (int r = 0; r < 32; r += 8) T[(size_t)(x0 + ty + r) * CH + y0 + tx] = f2bf(tile[tx][ty + r]);
}

// ---------------- generic NT GEMM: C[M,N] = scale * A[M,K] * Bt[N,K]^T (+bias) ----------------
// MODE 0: bf16 out, row-major [M][N]
// MODE 1: bf16 out, transposed per-4096-batch: out[(b*CH+n)*HW + (m&4095)]  (V path)
// MODE 2: f32 out + residual add (proj path)
// sA/sB/sC: per-blockIdx.z element strides for batched launches.
template <int MODE, int BM, int BN>
__global__ __launch_bounds__(256) void gemm_nt(const u16* __restrict__ A,
                                               const u16* __restrict__ Bt,
                                               const float* __restrict__ bias,
                                               const float* __restrict__ residual,
                                               void* __restrict__ Cout,
                                               int M, int N, int K, float scale,
                                               size_t sA, size_t sB, size_t sC) {
  constexpr int BK = 64;
  constexpr int LR = 72;              // LDS row stride (shorts): 144B, conflict-free
  constexpr int FM = BM / 32;         // frags per wave (2x2 wave grid)
  constexpr int FN = BN / 32;
  __shared__ __align__(16) u16 lA[BM * LR];
  __shared__ __align__(16) u16 lB[BN * LR];
  const int z = blockIdx.z;
  A += (size_t)z * sA;
  Bt += (size_t)z * sB;
  const int tid = threadIdx.x;
  const int lane = tid & 63, wid = tid >> 6;
  const int bm = blockIdx.y * BM, bn = blockIdx.x * BN;
  const int wm = (wid >> 1) * (BM / 2), wn = (wid & 1) * (BN / 2);
  const int r0 = lane & 15, h = lane >> 4;

  f32x4 acc[FM][FN] = {};

  for (int kt = 0; kt < K; kt += BK) {
    __syncthreads();
#pragma unroll
    for (int s = 0; s < BM * 8 / 256; ++s) {
      int cid = tid + s * 256;
      int row = cid >> 3, col = (cid & 7) * 8;
      bf16x8 v = *(const bf16x8*)(A + (size_t)(bm + row) * K + kt + col);
      *(bf16x8*)(&lA[row * LR + col]) = v;
    }
#pragma unroll
    for (int s = 0; s < BN * 8 / 256; ++s) {
      int cid = tid + s * 256;
      int row = cid >> 3, col = (cid & 7) * 8;
      bf16x8 v = *(const bf16x8*)(Bt + (size_t)(bn + row) * K + kt + col);
      *(bf16x8*)(&lB[row * LR + col]) = v;
    }
    __syncthreads();
#pragma unroll
    for (int kk = 0; kk < BK; kk += 32) {
      bf16x8 af[FM], bfr[FN];
#pragma unroll
      for (int i = 0; i < FM; ++i)
        af[i] = *(const bf16x8*)(&lA[(wm + i * 16 + r0) * LR + kk + h * 8]);
#pragma unroll
      for (int j = 0; j < FN; ++j)
        bfr[j] = *(const bf16x8*)(&lB[(wn + j * 16 + r0) * LR + kk + h * 8]);
#pragma unroll
      for (int i = 0; i < FM; ++i)
#pragma unroll
        for (int j = 0; j < FN; ++j)
          acc[i][j] = __builtin_amdgcn_mfma_f32_16x16x32_bf16(af[i], bfr[j], acc[i][j], 0, 0, 0);
    }
  }

  // epilogue: D layout col = lane&15, row = (lane>>4)*4 + r
#pragma unroll
  for (int j = 0; j < FN; ++j) {
    int n = bn + wn + j * 16 + r0;
    float bv = bias ? bias[n] : 0.0f;
#pragma unroll
    for (int i = 0; i < FM; ++i) {
      int m0 = bm + wm + i * 16 + h * 4;
      float v[4];
#pragma unroll
      for (int r = 0; r < 4; ++r) v[r] = acc[i][j][r] * scale + bv;
      if constexpr (MODE == 0) {
        u16* C = (u16*)Cout + (size_t)z * sC;
#pragma unroll
        for (int r = 0; r < 4; ++r) C[(size_t)(m0 + r) * N + n] = f2bf(v[r]);
      } else if constexpr (MODE == 1) {
        int bb = m0 >> 12, tl = m0 & (HW - 1);
        u16* C = (u16*)Cout + ((size_t)bb * CH + n) * HW + tl;
        union { u16 us[4]; uint2 q; } pk;
#pragma unroll
        for (int r = 0; r < 4; ++r) pk.us[r] = f2bf(v[r]);
        *(uint2*)C = pk.q;
      } else {
        float* C = (float*)Cout + (size_t)z * sC;
#pragma unroll
        for (int r = 0; r < 4; ++r) {
          size_t idx = (size_t)(m0 + r) * N + n;
          C[idx] = v[r] + residual[idx];
        }
      }
    }
  }
}

// ---------------- row softmax in-place on bf16 S [rows of HW] ----------------
__global__ void softmax_rows(u16* __restrict__ S) {
  const int t = threadIdx.x;
  u16* row = S + (size_t)blockIdx.x * HW;
  float v[16];
  bf16x8 a0 = *((const bf16x8*)row + t * 2);
  bf16x8 a1 = *((const bf16x8*)row + t * 2 + 1);
#pragma unroll
  for (int k = 0; k < 8; ++k) { v[k] = bf2f((u16)a0[k]); v[8 + k] = bf2f((u16)a1[k]); }
  float mx = v[0];
#pragma unroll
  for (int k = 1; k < 16; ++k) mx = fmaxf(mx, v[k]);
#pragma unroll
  for (int o = 32; o; o >>= 1) mx = fmaxf(mx, __shfl_xor(mx, o));
  __shared__ float redm[4], reds[4];
  int wid = t >> 6, lane = t & 63;
  if (lane == 0) redm[wid] = mx;
  __syncthreads();
  mx = fmaxf(fmaxf(redm[0], redm[1]), fmaxf(redm[2], redm[3]));
  float s = 0.f;
#pragma unroll
  for (int k = 0; k < 16; ++k) { v[k] = __expf(v[k] - mx); s += v[k]; }
#pragma unroll
  for (int o = 32; o; o >>= 1) s += __shfl_xor(s, o);
  if (lane == 0) reds[wid] = s;
  __syncthreads();
  s = reds[0] + reds[1] + reds[2] + reds[3];
  float inv = 1.0f / s;
  bf16x8 o0, o1;
#pragma unroll
  for (int k = 0; k < 8; ++k) {
    o0[k] = (short)f2bf(v[k] * inv);
    o1[k] = (short)f2bf(v[8 + k] * inv);
  }
  *((bf16x8*)row + t * 2) = o0;
  *((bf16x8*)row + t * 2 + 1) = o1;
}

extern "C" void kernel_launch(void* const* d_in, const int* in_sizes, int n_in,
                              void* d_out, int out_size, void* d_ws, size_t ws_size,
                              hipStream_t stream) {
  (void)in_sizes; (void)n_in; (void)out_size;
  const float* x     = (const float*)d_in[0];
  const float* gamma = (const float*)d_in[1];
  const float* beta  = (const float*)d_in[2];
  const float* Wq    = (const float*)d_in[3];
  const float* bq    = (const float*)d_in[4];
  const float* Wk    = (const float*)d_in[5];
  const float* bk    = (const float*)d_in[6];
  const float* Wv    = (const float*)d_in[7];
  const float* bv    = (const float*)d_in[8];
  const float* Wp    = (const float*)d_in[9];
  const float* bp    = (const float*)d_in[10];
  float* out = (float*)d_out;

  char* ws = (char*)d_ws;
  size_t off = 0;
  auto alloc = [&](size_t bytes) -> void* {
    void* p = ws + off;
    off += (bytes + 255) & ~(size_t)255;
    return p;
  };
  const size_t XN = (size_t)TOKENS * CH * 2;      // 16 MB
  const size_t WT = (size_t)CH * CH * 2;          // 0.5 MB
  const size_t SBB = (size_t)HW * HW * 2;         // 33.5 MB per batch
  const size_t need_all = 1024 + 5 * XN + 4 * WT + 4 * SBB;
  const bool big = ws_size >= need_all;           // deterministic across calls

  float2* stats = (float2*)alloc(128 * sizeof(float2));
  u16* xn  = (u16*)alloc(XN);
  u16* Qb  = (u16*)alloc(XN);
  u16* Kb  = (u16*)alloc(XN);
  u16* Vt  = (u16*)alloc(XN);   // [B][CH][HW]
  u16* Ob  = (u16*)alloc(XN);
  u16* WqT = (u16*)alloc(WT);
  u16* WkT = (u16*)alloc(WT);
  u16* WvT = (u16*)alloc(WT);
  u16* WpT = (u16*)alloc(WT);
  u16* Sb  = (u16*)alloc(big ? 4 * SBB : SBB);    // scores

  gn_stats<<<128, 256, 0, stream>>>(x, stats);
  gn_apply<<<TOKENS * CH / 8 / 256, 256, 0, stream>>>(x, gamma, beta, stats, xn);
  transpose_w<<<dim3(16, 16, 4), dim3(32, 8), 0, stream>>>(Wq, Wk, Wv, Wp, WqT, WkT, WvT, WpT);

  gemm_nt<0, 128, 128><<<dim3(CH / 128, TOKENS / 128), 256, 0, stream>>>(
      xn, WqT, bq, nullptr, Qb, TOKENS, CH, CH, 1.0f, 0, 0, 0);
  gemm_nt<0, 128, 128><<<dim3(CH / 128, TOKENS / 128), 256, 0, stream>>>(
      xn, WkT, bk, nullptr, Kb, TOKENS, CH, CH, 1.0f, 0, 0, 0);
  gemm_nt<1, 128, 128><<<dim3(CH / 128, TOKENS / 128), 256, 0, stream>>>(
      xn, WvT, bv, nullptr, Vt, TOKENS, CH, CH, 1.0f, 0, 0, 0);

  const float scl = 0.044194173824159216f;  // 1/sqrt(512)
  if (big) {
    // all 4 batches concurrently: S-GEMM (4096 blk), softmax (16384 blk), PV (1024 blk)
    gemm_nt<0, 128, 128><<<dim3(HW / 128, HW / 128, 4), 256, 0, stream>>>(
        Qb, Kb, nullptr, nullptr, Sb, HW, HW, CH, scl,
        (size_t)HW * CH, (size_t)HW * CH, (size_t)HW * HW);
    softmax_rows<<<TOKENS, 256, 0, stream>>>(Sb);
    gemm_nt<0, 64, 128><<<dim3(CH / 128, HW / 64, 4), 256, 0, stream>>>(
        Sb, Vt, nullptr, nullptr, Ob, HW, CH, HW, 1.0f,
        (size_t)HW * HW, (size_t)CH * HW, (size_t)HW * CH);
  } else {
    for (int b = 0; b < 4; ++b) {
      gemm_nt<0, 128, 128><<<dim3(HW / 128, HW / 128), 256, 0, stream>>>(
          Qb + (size_t)b * HW * CH, Kb + (size_t)b * HW * CH, nullptr, nullptr, Sb,
          HW, HW, CH, scl, 0, 0, 0);
      softmax_rows<<<HW, 256, 0, stream>>>(Sb);
      gemm_nt<0, 64, 128><<<dim3(CH / 128, HW / 64), 256, 0, stream>>>(
          Sb, Vt + (size_t)b * CH * HW, nullptr, nullptr, Ob + (size_t)b * HW * CH,
          HW, CH, HW, 1.0f, 0, 0, 0);
    }
  }

  gemm_nt<2, 128, 128><<<dim3(CH / 128, TOKENS / 128), 256, 0, stream>>>(
      Ob, WpT, bp, x, out, TOKENS, CH, CH, 1.0f, 0, 0, 0);
}

// Round 3
// 335.061 us; speedup vs baseline: 2.4573x; 1.2090x over previous
//
#include <hip/hip_runtime.h>

typedef unsigned short u16;
typedef short bf16x8 __attribute__((ext_vector_type(8)));
typedef float f32x4 __attribute__((ext_vector_type(4)));

#define CH 512
#define HW 4096
#define TOKENS 16384
#define NGRP 32

__device__ __forceinline__ u16 f2bf(float f) {
  unsigned u = __float_as_uint(f);
  u += 0x7fffu + ((u >> 16) & 1u);   // round-nearest-even
  return (u16)(u >> 16);
}
__device__ __forceinline__ float bf2f(u16 h) {
  return __uint_as_float(((unsigned)h) << 16);
}

// ---------------- GroupNorm stats: one block per (b,g) ----------------
__global__ void gn_stats(const float* __restrict__ x, float2* __restrict__ stats) {
  int bg = blockIdx.x;              // 0..127
  int b = bg >> 5, g = bg & 31;
  const float* base = x + (size_t)b * HW * CH + g * 16;
  float s = 0.f, s2 = 0.f;
  for (int p = threadIdx.x; p < HW; p += 256) {
    const float4* row = (const float4*)(base + (size_t)p * CH);
#pragma unroll
    for (int q = 0; q < 4; ++q) {
      float4 v = row[q];
      s += v.x + v.y + v.z + v.w;
      s2 += v.x * v.x + v.y * v.y + v.z * v.z + v.w * v.w;
    }
  }
#pragma unroll
  for (int o = 32; o; o >>= 1) { s += __shfl_down(s, o); s2 += __shfl_down(s2, o); }
  __shared__ float rs[4], rs2[4];
  int wid = threadIdx.x >> 6, lane = threadIdx.x & 63;
  if (lane == 0) { rs[wid] = s; rs2[wid] = s2; }
  __syncthreads();
  if (threadIdx.x == 0) {
    float S = rs[0] + rs[1] + rs[2] + rs[3];
    float S2 = rs2[0] + rs2[1] + rs2[2] + rs2[3];
    float mean = S * (1.f / 65536.f);
    float var = S2 * (1.f / 65536.f) - mean * mean;
    stats[bg] = make_float2(mean, rsqrtf(var + 1e-5f));
  }
}

// ---------------- GroupNorm apply -> xn (bf16) ----------------
__global__ void gn_apply(const float* __restrict__ x, const float* __restrict__ gamma,
                         const float* __restrict__ beta, const float2* __restrict__ stats,
                         u16* __restrict__ xn) {
  size_t i = (size_t)blockIdx.x * blockDim.x + threadIdx.x;  // chunk of 8 elems
  size_t e0 = i * 8;
  int c = (int)(e0 & (CH - 1));
  size_t t = e0 >> 9;
  int b = (int)(t >> 12);
  float2 st = stats[b * NGRP + (c >> 4)];
  float4 v0 = *(const float4*)(x + t * CH + c);
  float4 v1 = *(const float4*)(x + t * CH + c + 4);
  float4 g0 = *(const float4*)(gamma + c);
  float4 g1 = *(const float4*)(gamma + c + 4);
  float4 b0 = *(const float4*)(beta + c);
  float4 b1 = *(const float4*)(beta + c + 4);
  float o[8];
  o[0] = (v0.x - st.x) * st.y * g0.x + b0.x;
  o[1] = (v0.y - st.x) * st.y * g0.y + b0.y;
  o[2] = (v0.z - st.x) * st.y * g0.z + b0.z;
  o[3] = (v0.w - st.x) * st.y * g0.w + b0.w;
  o[4] = (v1.x - st.x) * st.y * g1.x + b1.x;
  o[5] = (v1.y - st.x) * st.y * g1.y + b1.y;
  o[6] = (v1.z - st.x) * st.y * g1.z + b1.z;
  o[7] = (v1.w - st.x) * st.y * g1.w + b1.w;
  union { u16 us[8]; uint4 q; } pk;
#pragma unroll
  for (int k = 0; k < 8; ++k) pk.us[k] = f2bf(o[k]);
  *(uint4*)(xn + e0) = pk.q;
}

// ---------------- transpose 512x512 weights fp32 -> bf16 (T[d][c] = W[c][d]) ----------------
__global__ void transpose_w(const float* __restrict__ W0, const float* __restrict__ W1,
                            const float* __restrict__ W2, const float* __restrict__ W3,
                            u16* __restrict__ T0, u16* __restrict__ T1,
                            u16* __restrict__ T2, u16* __restrict__ T3) {
  const float* W; u16* T;
  switch (blockIdx.z) {
    case 0: W = W0; T = T0; break;
    case 1: W = W1; T = T1; break;
    case 2: W = W2; T = T2; break;
    default: W = W3; T = T3; break;
  }
  __shared__ float tile[32][33];
  int tx = threadIdx.x, ty = threadIdx.y;
  int x0 = blockIdx.x * 32, y0 = blockIdx.y * 32;
#pragma unroll
  for (int r = 0; r < 32; r += 8) tile[ty + r][tx] = W[(size_t)(y0 + ty + r) * CH + x0 + tx];
  __syncthreads();
#pragma unroll
  for (int r = 0; r < 32; r += 8) T[(size_t)(x0 + ty + r) * CH + y0 + tx] = f2bf(tile[tx][ty + r]);
}

// ---------------- generic NT GEMM: C[M,N] = scale * A[M,K] * Bt[N,K]^T ----------------
// MODE 1: bf16 out, transposed per-4096-batch: out[(bb*CH+n)*HW + (m&4095)]  (V layout)
// MODE 2: f32 out + residual add (proj path)
// MODE 3: fused QKV epilogue (N=1536; chunk 0->Cout rowmajor, 1->Cout2 rowmajor, 2->Cout3 V-layout)
// MODE 4: PV with on-the-fly row-sum of A (exp'd scores) and 1/l normalize; XCD-swizzled tiles
// MODE 6: bf16 rowmajor with exp() epilogue (S-GEMM; scale pre-applied)
template <int MODE, int BM, int BN>
__global__ __launch_bounds__(256) void gemm_nt(const u16* __restrict__ A,
                                               const u16* __restrict__ Bt,
                                               const float* __restrict__ bias,
                                               const float* __restrict__ bias2,
                                               const float* __restrict__ bias3,
                                               const float* __restrict__ residual,
                                               void* __restrict__ Cout,
                                               void* __restrict__ Cout2,
                                               void* __restrict__ Cout3,
                                               int M, int N, int K, float scale,
                                               size_t sA, size_t sB, size_t sC) {
  constexpr int BK = 64;
  constexpr int LR = 72;              // LDS row stride (shorts): 144B, conflict-free
  constexpr int FM = BM / 32;         // frags per wave (2x2 wave grid)
  constexpr int FN = BN / 32;
  __shared__ __align__(16) u16 lA[BM * LR];
  __shared__ __align__(16) u16 lB[BN * LR];
  __shared__ float lsum[(MODE == 4) ? BM : 1];

  int bm, bn, z;
  if constexpr (MODE == 4) {
    // 1-D grid; group g = (y,z); the 8 n-blocks of a group land on one XCD consecutively
    int p = blockIdx.x;
    if (gridDim.x == 2048) {
      int xcd = p & 7, r = p >> 3;
      int xi = r & 7, q = r >> 3;
      int g = (q << 3) | xcd;          // 0..255, g%8 == xcd
      bn = xi * BN; bm = (g & 63) * BM; z = g >> 6;
    } else {                            // fallback: plain decode, z=0
      bn = (blockIdx.x & 7) * BN; bm = (blockIdx.x >> 3) * BM; z = 0;
    }
  } else {
    z = blockIdx.z; bm = blockIdx.y * BM; bn = blockIdx.x * BN;
  }
  A += (size_t)z * sA;
  Bt += (size_t)z * sB;
  const int tid = threadIdx.x;
  const int lane = tid & 63, wid = tid >> 6;
  const int wm = (wid >> 1) * (BM / 2), wn = (wid & 1) * (BN / 2);
  const int r0 = lane & 15, h = lane >> 4;

  f32x4 acc[FM][FN] = {};
  float rsum[2] = {0.f, 0.f};          // MODE 4: partial row-sums (rows tid>>3, 32+tid>>3)

  for (int kt = 0; kt < K; kt += BK) {
    __syncthreads();
#pragma unroll
    for (int s = 0; s < BM * 8 / 256; ++s) {
      int cid = tid + s * 256;
      int row = cid >> 3, col = (cid & 7) * 8;
      bf16x8 v = *(const bf16x8*)(A + (size_t)(bm + row) * K + kt + col);
      if constexpr (MODE == 4) {
        float t = 0.f;
#pragma unroll
        for (int k = 0; k < 8; ++k) t += bf2f((u16)v[k]);
        rsum[s] += t;
      }
      *(bf16x8*)(&lA[row * LR + col]) = v;
    }
#pragma unroll
    for (int s = 0; s < BN * 8 / 256; ++s) {
      int cid = tid + s * 256;
      int row = cid >> 3, col = (cid & 7) * 8;
      bf16x8 v = *(const bf16x8*)(Bt + (size_t)(bn + row) * K + kt + col);
      *(bf16x8*)(&lB[row * LR + col]) = v;
    }
    __syncthreads();
#pragma unroll
    for (int kk = 0; kk < BK; kk += 32) {
      bf16x8 af[FM], bfr[FN];
#pragma unroll
      for (int i = 0; i < FM; ++i)
        af[i] = *(const bf16x8*)(&lA[(wm + i * 16 + r0) * LR + kk + h * 8]);
#pragma unroll
      for (int j = 0; j < FN; ++j)
        bfr[j] = *(const bf16x8*)(&lB[(wn + j * 16 + r0) * LR + kk + h * 8]);
#pragma unroll
      for (int i = 0; i < FM; ++i)
#pragma unroll
        for (int j = 0; j < FN; ++j)
          acc[i][j] = __builtin_amdgcn_mfma_f32_16x16x32_bf16(af[i], bfr[j], acc[i][j], 0, 0, 0);
    }
  }

  if constexpr (MODE == 4) {
    // reduce partial row-sums across the 8 staging threads of each row
#pragma unroll
    for (int w = 1; w < 8; w <<= 1) {
      rsum[0] += __shfl_xor(rsum[0], w);
      rsum[1] += __shfl_xor(rsum[1], w);
    }
    if ((tid & 7) == 0) { lsum[tid >> 3] = rsum[0]; lsum[(tid >> 3) + 32] = rsum[1]; }
    __syncthreads();
  }

  // epilogue: D layout col = lane&15, row = (lane>>4)*4 + r
#pragma unroll
  for (int j = 0; j < FN; ++j) {
    int n = bn + wn + j * 16 + r0;
    float bvv;
    if constexpr (MODE == 3) {
      int nn = n & 511, ch = n >> 9;
      bvv = ch == 0 ? bias[nn] : ch == 1 ? bias2[nn] : bias3[nn];
    } else {
      bvv = bias ? bias[n] : 0.0f;
    }
#pragma unroll
    for (int i = 0; i < FM; ++i) {
      int m0 = bm + wm + i * 16 + h * 4;
      float v[4];
#pragma unroll
      for (int r = 0; r < 4; ++r) v[r] = acc[i][j][r] * scale + bvv;
      if constexpr (MODE == 1) {
        int bb = m0 >> 12, tl = m0 & (HW - 1);
        u16* C = (u16*)Cout + ((size_t)bb * CH + n) * HW + tl;
        union { u16 us[4]; uint2 q; } pk;
#pragma unroll
        for (int r = 0; r < 4; ++r) pk.us[r] = f2bf(v[r]);
        *(uint2*)C = pk.q;
      } else if constexpr (MODE == 2) {
        float* C = (float*)Cout + (size_t)z * sC;
#pragma unroll
        for (int r = 0; r < 4; ++r) {
          size_t idx = (size_t)(m0 + r) * N + n;
          C[idx] = v[r] + residual[idx];
        }
      } else if constexpr (MODE == 3) {
        int nn = n & 511, ch = n >> 9;
        if (ch == 2) {                  // V: transposed layout
          int bb = m0 >> 12, tl = m0 & (HW - 1);
          u16* C = (u16*)Cout3 + ((size_t)bb * CH + nn) * HW + tl;
          union { u16 us[4]; uint2 q; } pk;
#pragma unroll
          for (int r = 0; r < 4; ++r) pk.us[r] = f2bf(v[r]);
          *(uint2*)C = pk.q;
        } else {
          u16* C = (u16*)(ch == 0 ? Cout : Cout2);
#pragma unroll
          for (int r = 0; r < 4; ++r) C[(size_t)(m0 + r) * CH + nn] = f2bf(v[r]);
        }
      } else if constexpr (MODE == 4) {
        u16* C = (u16*)Cout + (size_t)z * sC;
#pragma unroll
        for (int r = 0; r < 4; ++r) {
          int lm = wm + i * 16 + h * 4 + r;
          C[(size_t)(m0 + r) * N + n] = f2bf(v[r] * (1.0f / lsum[lm]));
        }
      } else {                          // MODE 6: exp epilogue
        u16* C = (u16*)Cout + (size_t)z * sC;
#pragma unroll
        for (int r = 0; r < 4; ++r) C[(size_t)(m0 + r) * N + n] = f2bf(__expf(v[r]));
      }
    }
  }
}

extern "C" void kernel_launch(void* const* d_in, const int* in_sizes, int n_in,
                              void* d_out, int out_size, void* d_ws, size_t ws_size,
                              hipStream_t stream) {
  (void)in_sizes; (void)n_in; (void)out_size;
  const float* x     = (const float*)d_in[0];
  const float* gamma = (const float*)d_in[1];
  const float* beta  = (const float*)d_in[2];
  const float* Wq    = (const float*)d_in[3];
  const float* bq    = (const float*)d_in[4];
  const float* Wk    = (const float*)d_in[5];
  const float* bk    = (const float*)d_in[6];
  const float* Wv    = (const float*)d_in[7];
  const float* bv    = (const float*)d_in[8];
  const float* Wp    = (const float*)d_in[9];
  const float* bp    = (const float*)d_in[10];
  float* out = (float*)d_out;

  char* ws = (char*)d_ws;
  size_t off = 0;
  auto alloc = [&](size_t bytes) -> void* {
    void* p = ws + off;
    off += (bytes + 255) & ~(size_t)255;
    return p;
  };
  const size_t XN = (size_t)TOKENS * CH * 2;      // 16 MB
  const size_t WT = (size_t)CH * CH * 2;          // 0.5 MB
  const size_t SBB = (size_t)HW * HW * 2;         // 33.5 MB per batch
  const size_t need_all = 1024 + 5 * XN + 4 * WT + 4 * SBB;
  const bool big = ws_size >= need_all;           // deterministic across calls

  float2* stats = (float2*)alloc(128 * sizeof(float2));
  u16* xn   = (u16*)alloc(XN);
  u16* Qb   = (u16*)alloc(XN);
  u16* Kb   = (u16*)alloc(XN);
  u16* Vt   = (u16*)alloc(XN);   // [B][CH][HW]
  u16* Ob   = (u16*)alloc(XN);
  u16* Wqkv = (u16*)alloc(3 * WT);  // [Wq^T; Wk^T; Wv^T] stacked along rows
  u16* WpT  = (u16*)alloc(WT);
  u16* Sb   = (u16*)alloc(big ? 4 * SBB : SBB);   // exp'd scores

  gn_stats<<<128, 256, 0, stream>>>(x, stats);
  gn_apply<<<TOKENS * CH / 8 / 256, 256, 0, stream>>>(x, gamma, beta, stats, xn);
  transpose_w<<<dim3(16, 16, 4), dim3(32, 8), 0, stream>>>(
      Wq, Wk, Wv, Wp, Wqkv, Wqkv + (size_t)CH * CH, Wqkv + 2 * (size_t)CH * CH, WpT);

  // fused QKV: one GEMM, N=1536, epilogue routes chunks
  gemm_nt<3, 128, 128><<<dim3(1536 / 128, TOKENS / 128), 256, 0, stream>>>(
      xn, Wqkv, bq, bk, bv, nullptr, Qb, Kb, Vt, TOKENS, 1536, CH, 1.0f, 0, 0, 0);

  const float scl = 0.044194173824159216f;  // 1/sqrt(512)
  if (big) {
    // S = exp(Q K^T * scale) for all 4 batches
    gemm_nt<6, 128, 128><<<dim3(HW / 128, HW / 128, 4), 256, 0, stream>>>(
        Qb, Kb, nullptr, nullptr, nullptr, nullptr, Sb, nullptr, nullptr,
        HW, HW, CH, scl, (size_t)HW * CH, (size_t)HW * CH, (size_t)HW * HW);
    // O = (S V) / rowsum(S), XCD-swizzled
    gemm_nt<4, 64, 64><<<dim3(2048), 256, 0, stream>>>(
        Sb, Vt, nullptr, nullptr, nullptr, nullptr, Ob, nullptr, nullptr,
        HW, CH, HW, 1.0f, (size_t)HW * HW, (size_t)CH * HW, (size_t)HW * CH);
  } else {
    for (int b = 0; b < 4; ++b) {
      gemm_nt<6, 128, 128><<<dim3(HW / 128, HW / 128), 256, 0, stream>>>(
          Qb + (size_t)b * HW * CH, Kb + (size_t)b * HW * CH, nullptr, nullptr, nullptr,
          nullptr, Sb, nullptr, nullptr, HW, HW, CH, scl, 0, 0, 0);
      gemm_nt<4, 64, 64><<<dim3(512), 256, 0, stream>>>(
          Sb, Vt + (size_t)b * CH * HW, nullptr, nullptr, nullptr, nullptr,
          Ob + (size_t)b * HW * CH, nullptr, nullptr, HW, CH, HW, 1.0f, 0, 0, 0);
    }
  }

  gemm_nt<2, 128, 128><<<dim3(CH / 128, TOKENS / 128), 256, 0, stream>>>(
      Ob, WpT, bp, nullptr, nullptr, x, out, nullptr, nullptr,
      TOKENS, CH, CH, 1.0f, 0, 0, 0);
}